// Round 9
// baseline (339.194 us; speedup 1.0000x reference)
//
#include <hip/hip_runtime.h>
#include <math.h>

#define S_LEN 2048
#define NH 16
#define DN 128
#define DR 64
#define DV 128
#define QL 1536
#define KL 512
#define FUSED_N 2112
#define FPAD 2176            // fused padded to 17*128
#define QB_N 3072
#define KVB_N 4096
#define HD_QK 192
#define EPS_RMS 1e-6f

typedef _Float16 f16;
typedef _Float16 half8 __attribute__((ext_vector_type(8)));
typedef _Float16 half4 __attribute__((ext_vector_type(4)));
typedef float floatx4 __attribute__((ext_vector_type(4)));

__device__ __forceinline__ void async16(const f16* gp, f16* lp)
{
    __builtin_amdgcn_global_load_lds(
        (const __attribute__((address_space(1))) void*)gp,
        (__attribute__((address_space(3))) void*)lp, 16, 0, 0);
}

// ---------------------------------------------------------------------------
// GEMM core: C[128 x 64] tile of A[M,K] @ Bt[N,K]^T.  BK=64, dbuf async.
// sm layout per buf (f16): A [0,8192) = 128x64, B [8192,12288) = 64x64.
// 4 waves in 2x2: wave = 64 rows x 32 cols = 4x2 MFMAs of 16x16x32.
// ---------------------------------------------------------------------------
template <int OUT_F16>
__device__ __forceinline__ void gemm_core(
    const f16* __restrict__ A, const f16* __restrict__ Bt,
    void* __restrict__ Cv, int N, int K, int bm, int bn, f16* sm)
{
    const int tid = threadIdx.x;
    const int wv = tid >> 6, lane = tid & 63;
    const int quad = lane >> 4, l15 = lane & 15;
    const int wr = wv >> 1, wc = wv & 1;
    const int srow = lane >> 3, sc = lane & 7;

    size_t aoff[4]; int lda[4];
    #pragma unroll
    for (int t = 0; t < 4; ++t) {
        int rl = wv * 32 + t * 8 + srow;
        int ch = sc ^ (rl & 7);
        aoff[t] = (size_t)(bm + rl) * K + ch * 8;
        lda[t] = (wv * 32 + t * 8) * 64;
    }
    size_t boff[2]; int ldb[2];
    #pragma unroll
    for (int t = 0; t < 2; ++t) {
        int rl = wv * 16 + t * 8 + srow;
        int ch = sc ^ (rl & 7);
        boff[t] = (size_t)(bn + rl) * K + ch * 8;
        ldb[t] = 8192 + (wv * 16 + t * 8) * 64;
    }

    #pragma unroll
    for (int t = 0; t < 4; ++t) async16(A  + aoff[t], &sm[lda[t]]);
    #pragma unroll
    for (int t = 0; t < 2; ++t) async16(Bt + boff[t], &sm[ldb[t]]);

    floatx4 acc[4][2] = {};
    const int nsteps = K >> 6;

    for (int step = 0; step < nsteps; ++step) {
        const int cur = step & 1;
        __syncthreads();
        if (step + 1 < nsteps) {
            const int k0n = (step + 1) << 6;
            f16* nb = sm + (1 - cur) * 12288;
            #pragma unroll
            for (int t = 0; t < 4; ++t) async16(A  + aoff[t] + k0n, nb + lda[t]);
            #pragma unroll
            for (int t = 0; t < 2; ++t) async16(Bt + boff[t] + k0n, nb + ldb[t]);
        }
        const f16* As = sm + cur * 12288;
        const f16* Bs = As + 8192;

        #pragma unroll
        for (int ks = 0; ks < 2; ++ks) {
            half8 av[4], bv[2];
            #pragma unroll
            for (int i = 0; i < 4; ++i) {
                int m = wr * 64 + i * 16 + l15;
                av[i] = *(const half8*)&As[m * 64 + ((ks * 4 + quad) ^ (m & 7)) * 8];
            }
            #pragma unroll
            for (int j = 0; j < 2; ++j) {
                int n = wc * 32 + j * 16 + l15;
                bv[j] = *(const half8*)&Bs[n * 64 + ((ks * 4 + quad) ^ (n & 7)) * 8];
            }
            #pragma unroll
            for (int i = 0; i < 4; ++i)
                #pragma unroll
                for (int j = 0; j < 2; ++j)
                    acc[i][j] = __builtin_amdgcn_mfma_f32_16x16x32_f16(
                        av[i], bv[j], acc[i][j], 0, 0, 0);
        }
    }

    #pragma unroll
    for (int i = 0; i < 4; ++i) {
        int rbase = bm + wr * 64 + i * 16 + quad * 4;
        #pragma unroll
        for (int j = 0; j < 2; ++j) {
            int cidx = bn + wc * 32 + j * 16 + l15;
            #pragma unroll
            for (int rr = 0; rr < 4; ++rr) {
                if (OUT_F16)
                    ((f16*)Cv)[(size_t)(rbase + rr) * N + cidx] = (f16)acc[i][j][rr];
                else
                    ((float*)Cv)[(size_t)(rbase + rr) * N + cidx] = acc[i][j][rr];
            }
        }
    }
}

template <int OUT_F16>
__global__ __launch_bounds__(256) void gemm_mfma(
    const f16* __restrict__ A, const f16* __restrict__ Bt,
    void* __restrict__ Cv, int N, int K)
{
    __shared__ f16 sm[2 * 12288];
    gemm_core<OUT_F16>(A, Bt, Cv, N, K, blockIdx.y * 128, blockIdx.x * 64, sm);
}

// Fused independent GEMMs: x<48 -> qbuf = q_n @ wqb^T ; else kvbuf = kv_n @ wkvb^T
__global__ __launch_bounds__(256) void gemm_dual(
    const f16* __restrict__ A1, const f16* __restrict__ B1, f16* __restrict__ C1,
    const f16* __restrict__ A2, const f16* __restrict__ B2, f16* __restrict__ C2)
{
    __shared__ f16 sm[2 * 12288];
    int bx = blockIdx.x;
    if (bx < 48)
        gemm_core<1>(A1, B1, C1, QB_N, QL, blockIdx.y * 128, bx * 64, sm);
    else
        gemm_core<1>(A2, B2, C2, KVB_N, KL, blockIdx.y * 128, (bx - 48) * 64, sm);
}

// ---------------------------------------------------------------------------
// Fused prep: cvt(hidden->f16) + 4x transpose-convert weights.
// ---------------------------------------------------------------------------
__device__ __forceinline__ void tconv_core(
    const float* __restrict__ in, f16* __restrict__ out,
    int K, int N, int n0, int k0, float t[32][33])
{
    const int c = threadIdx.x & 31, r8 = threadIdx.x >> 5;
    #pragma unroll
    for (int i = 0; i < 4; ++i) {
        int r = r8 + i * 8;
        int gc = n0 + c;
        t[r][c] = (gc < N) ? in[(size_t)(k0 + r) * N + gc] : 0.f;
    }
    __syncthreads();
    #pragma unroll
    for (int i = 0; i < 4; ++i) {
        int r = r8 + i * 8;
        out[(size_t)(n0 + r) * K + k0 + c] = (f16)t[c][r];
    }
}

__global__ __launch_bounds__(256) void prep_k(
    const float* __restrict__ hidden, f16* __restrict__ hid_h,
    const float* __restrict__ w_kv_a, f16* __restrict__ wkva_t,
    const float* __restrict__ w_qb,   f16* __restrict__ wqb_t,
    const float* __restrict__ w_kvb,  f16* __restrict__ wkvb_t,
    const float* __restrict__ w_o,    f16* __restrict__ wo_t)
{
    __shared__ float t[32][33];
    int b = blockIdx.x;
    if (b < 4096) {
        int i = b * 256 + threadIdx.x;
        float4 v = ((const float4*)hidden)[i];
        half4 h;
        h[0] = (f16)v.x; h[1] = (f16)v.y; h[2] = (f16)v.z; h[3] = (f16)v.w;
        ((half4*)hid_h)[i] = h;
    } else if (b < 8448) {
        int r = b - 4096;
        tconv_core(w_kv_a, wkva_t, 2048, FUSED_N, (r % 68) * 32, (r / 68) * 32, t);
    } else if (b < 13056) {
        int r = b - 8448;
        tconv_core(w_qb, wqb_t, QL, QB_N, (r % 96) * 32, (r / 96) * 32, t);
    } else if (b < 15104) {
        int r = b - 13056;
        tconv_core(w_kvb, wkvb_t, KL, KVB_N, (r % 128) * 32, (r / 128) * 32, t);
    } else {
        int r = b - 15104;
        tconv_core(w_o, wo_t, 2048, 2048, (r % 64) * 32, (r / 64) * 32, t);
    }
}

// ---------------------------------------------------------------------------
// Fused RMSNorm (rows 0..2047 -> q_n, 2048..4095 -> kv_n)
// ---------------------------------------------------------------------------
__global__ __launch_bounds__(256) void rmsnorm_k(
    const float* __restrict__ fused, const float* __restrict__ q_gamma,
    const float* __restrict__ kv_gamma, f16* __restrict__ q_n,
    f16* __restrict__ kv_n)
{
    const int b = blockIdx.x;
    const bool isq = b < 2048;
    const int row = isq ? b : b - 2048;
    const int ncols = isq ? QL : KL;
    const float* x = fused + (size_t)row * FPAD + (isq ? 0 : QL);
    const float* gamma = isq ? q_gamma : kv_gamma;
    f16* out = isq ? q_n : kv_n;

    float ss = 0.f;
    for (int c = threadIdx.x; c < ncols; c += 256) {
        float v = x[c];
        ss += v * v;
    }
    #pragma unroll
    for (int off = 32; off > 0; off >>= 1) ss += __shfl_down(ss, off);

    __shared__ float warp_s[4];
    __shared__ float scale_s;
    const int wid = threadIdx.x >> 6;
    if ((threadIdx.x & 63) == 0) warp_s[wid] = ss;
    __syncthreads();
    if (threadIdx.x == 0) {
        float tt = warp_s[0] + warp_s[1] + warp_s[2] + warp_s[3];
        scale_s = rsqrtf(tt / (float)ncols + EPS_RMS);
    }
    __syncthreads();
    const float sc = scale_s;
    for (int c = threadIdx.x; c < ncols; c += 256)
        out[(size_t)row * ncols + c] = (f16)(x[c] * gamma[c] * sc);
}

// ---------------------------------------------------------------------------
// RoPE helper
// ---------------------------------------------------------------------------
__device__ __forceinline__ float rope_one(int s, int d, float x, float other)
{
    const int j = d & 31;
    const float invf = expf(-0.28782313662425572f * (float)j); // 10000^(-j/32)
    const float ang = (float)s * invf;
    float sn, cs;
    sincosf(ang, &sn, &cs);
    float rot = (d < 32) ? -other : other;
    return x * cs + rot * sn;
}

// ---------------------------------------------------------------------------
// Fused post: rope_q + kfull + vt.
// ---------------------------------------------------------------------------
__global__ __launch_bounds__(256) void post_k(
    f16* __restrict__ q, const f16* __restrict__ kv,
    const float* __restrict__ fused, f16* __restrict__ kfull,
    f16* __restrict__ vt)
{
    __shared__ f16 t[32][33];
    int b = blockIdx.x;
    if (b < 8192) {
        const int s = b & 2047;
        const int h = (b >> 11) * 4 + (threadIdx.x >> 6);
        const int d = threadIdx.x & 63;
        f16* base = q + (size_t)s * QB_N + h * HD_QK + DN;
        float x = (float)base[d];
        float other = (float)((d < 32) ? base[d + 32] : base[d - 32]);
        base[d] = (f16)rope_one(s, d, x, other);
    } else if (b < 11264) {
        int n = (b - 8192) * 256 + threadIdx.x;   // < 16*2048*24
        int c8 = n % 24;
        int s = (n / 24) & 2047;
        int h = n / (24 * 2048);
        half8 v;
        if (c8 < 16) {
            v = *(const half8*)&kv[(size_t)s * KVB_N + h * 256 + c8 * 8];
        } else {
            const float* src = fused + (size_t)s * FPAD + (QL + KL);
            int dbase = (c8 - 16) * 8;
            #pragma unroll
            for (int j = 0; j < 8; ++j) {
                int d = dbase + j;
                float x = src[d];
                float other = src[(d < 32) ? d + 32 : d - 32];
                v[j] = (f16)rope_one(s, d, x, other);
            }
        }
        *(half8*)&kfull[((size_t)h * S_LEN + s) * HD_QK + c8 * 8] = v;
    } else {
        int r = b - 11264;
        const int s0 = (r & 63) * 32, d0 = ((r >> 6) & 3) * 32, h = r >> 8;
        const int tid = threadIdx.x;
        {
            const int c = tid & 31, rb = tid >> 5;
            #pragma unroll
            for (int i = 0; i < 4; ++i) {
                int rr = rb + i * 8;
                t[rr][c] = kv[(size_t)(s0 + rr) * KVB_N + h * 256 + 128 + d0 + c];
            }
        }
        __syncthreads();
        {
            const int d = tid >> 3, s4 = tid & 7;
            half4 v;
            v[0] = t[s4 * 4 + 0][d];
            v[1] = t[s4 * 4 + 1][d];
            v[2] = t[s4 * 4 + 2][d];
            v[3] = t[s4 * 4 + 3][d];
            *(half4*)&vt[((size_t)h * DV + d0 + d) * S_LEN + s0 + s4 * 4] = v;
        }
    }
}

// ---------------------------------------------------------------------------
// MFMA flash attention (causal), split-K=2, SINGLE-buffered K/V staging for
// max residency: LDS = 25600 B -> 6 blocks/CU (24 waves).  Per tile:
// [barrier: compute done][issue async K/V][barrier: drain][compute].
// Cross-block overlap (6 chains/CU) hides the exposed L2 latency.
//
// LDS map (f16 units, total 12800 = 25.6 KB):
//   Ks [0,6144) 32x192 | VTs [6144,10240) 128x32 | P [10240,12800) 4x640
//   Q staging [0,12288) pre-loop only (overlaps Ks/VTs/P; dead after preload)
// ---------------------------------------------------------------------------
__global__ __launch_bounds__(256) void attn_mfma_k(
    const f16* __restrict__ q,      // [S][3072]
    const f16* __restrict__ kfull,  // [NH][S][192]
    const f16* __restrict__ vt,     // [NH][128][S]
    f16* __restrict__ part_o,       // [2][S][2048]
    float* __restrict__ part_ml)    // [2][NH][S][2]
{
    __shared__ f16 sm[12800];

    const int tid = threadIdx.x;
    const int w = tid >> 6, lane = tid & 63;
    const int quad = lane >> 4, l15 = lane & 15;
    const int wbase = w * 64;
    const int h = blockIdx.y;
    const int z = blockIdx.z;
    const int qb = (blockIdx.y < 8) ? (int)blockIdx.x : 31 - (int)blockIdx.x;
    const int q0 = qb * 64;
    const int kt_begin = z ? (qb + 1) : 0;
    const int kt_end   = z ? (2 * qb + 2) : (qb + 1);
    const float scale2 = 0.10411755f;   // (1/sqrt(192)) * log2(e)

    const f16* kf_h = kfull + (size_t)h * S_LEN * HD_QK;
    const f16* vt_h = vt + (size_t)h * DV * S_LEN;

    // staging slot decodes (k0-independent)
    int koff[3];
    #pragma unroll
    for (int j = 0; j < 3; ++j) {
        int sig = j * 256 + tid;
        int r = sig / 24, cs = sig - r * 24;
        int ch = (cs & 24) | ((cs & 7) ^ (r & 7));
        koff[j] = r * HD_QK + ch * 8;
    }
    int voff[2];
    #pragma unroll
    for (int j = 0; j < 2; ++j) {
        int sig = j * 256 + tid;
        int rv = sig >> 2, c = (sig & 3) ^ ((rv >> 1) & 3);
        voff[j] = rv * S_LEN + c * 8;
    }

    // stage Q (64x192) -> sm[0,12288) async, then preload fragments
    #pragma unroll
    for (int j = 0; j < 6; ++j) {
        int sig = j * 256 + tid;
        int r = sig / 24, cs = sig - r * 24;
        int ch = (cs & 24) | ((cs & 7) ^ (r & 7));
        async16(q + (size_t)(q0 + r) * QB_N + h * HD_QK + ch * 8,
                sm + (j * 256 + wbase) * 8);
    }
    __syncthreads();

    half8 qf[6];
    const int qrow = w * 16 + l15;
    #pragma unroll
    for (int kd = 0; kd < 6; ++kd) {
        int c = kd * 4 + quad;
        int cs = (c & 24) | ((c & 7) ^ (qrow & 7));
        qf[kd] = *(const half8*)&sm[(qrow * 24 + cs) * 8];
    }

    half8 ones_h;
    #pragma unroll
    for (int j = 0; j < 8; ++j) ones_h[j] = (f16)1.0f;

    floatx4 o[8] = {};
    floatx4 o_l = {};
    float m_i[4];
    #pragma unroll
    for (int r = 0; r < 4; ++r) m_i[r] = -1e30f;

    const int qrow_min = q0 + w * 16;
    f16* Pw = sm + 10240 + w * 640;
    const f16* kb = sm;
    const f16* vb = sm + 6144;

    for (int kt = kt_begin; kt < kt_end; ++kt) {
        const int k0 = kt * 32;
        __syncthreads();        // all waves done with previous tile's K/V (and Q preload)
        {
            const f16* kg = kf_h + (size_t)k0 * HD_QK;
            const f16* vg = vt_h + k0;
            #pragma unroll
            for (int j = 0; j < 3; ++j) async16(kg + koff[j], sm + (j * 256 + wbase) * 8);
            #pragma unroll
            for (int j = 0; j < 2; ++j) async16(vg + voff[j], sm + 6144 + (j * 256 + wbase) * 8);
        }
        __syncthreads();        // loads drained
        if (k0 > qrow_min + 15) continue;   // causally done for this wave

        // QK^T (16 x 32)
        floatx4 s0 = {}, s1 = {};
        #pragma unroll
        for (int kd = 0; kd < 6; ++kd) {
            int c = kd * 4 + quad;
            int cs = (c & 24) | ((c & 7) ^ (l15 & 7));
            half8 b0 = *(const half8*)&kb[(l15 * 24 + cs) * 8];
            half8 b1 = *(const half8*)&kb[((l15 + 16) * 24 + cs) * 8];
            s0 = __builtin_amdgcn_mfma_f32_16x16x32_f16(qf[kd], b0, s0, 0, 0, 0);
            s1 = __builtin_amdgcn_mfma_f32_16x16x32_f16(qf[kd], b1, s1, 0, 0, 0);
        }

        // mask + scale (log2 domain) + row-max
        const bool nm = (k0 + 31 > qrow_min);
        float mt[4];
        #pragma unroll
        for (int r = 0; r < 4; ++r) {
            float v0 = s0[r] * scale2, v1 = s1[r] * scale2;
            if (nm) {
                int row = qrow_min + quad * 4 + r;
                if (k0 + l15 > row)      v0 = -1e30f;
                if (k0 + 16 + l15 > row) v1 = -1e30f;
            }
            s0[r] = v0; s1[r] = v1;
            mt[r] = fmaxf(v0, v1);
        }
        #pragma unroll
        for (int r = 0; r < 4; ++r) {
            mt[r] = fmaxf(mt[r], __shfl_xor(mt[r], 1));
            mt[r] = fmaxf(mt[r], __shfl_xor(mt[r], 2));
            mt[r] = fmaxf(mt[r], __shfl_xor(mt[r], 4));
            mt[r] = fmaxf(mt[r], __shfl_xor(mt[r], 8));
        }
        float alpha[4];
        #pragma unroll
        for (int r = 0; r < 4; ++r) {
            float mn = fmaxf(m_i[r], mt[r]);
            alpha[r] = __builtin_exp2f(m_i[r] - mn);
            m_i[r] = mn;
            s0[r] = __builtin_exp2f(s0[r] - mn);
            s1[r] = __builtin_exp2f(s1[r] - mn);
        }

        // P: C-layout -> wave-private LDS
        #pragma unroll
        for (int r = 0; r < 4; ++r) {
            Pw[(quad * 4 + r) * 40 + l15]      = (f16)s0[r];
            Pw[(quad * 4 + r) * 40 + 16 + l15] = (f16)s1[r];
        }

        // rescale O and l
        #pragma unroll
        for (int nb = 0; nb < 8; ++nb)
            #pragma unroll
            for (int r = 0; r < 4; ++r) o[nb][r] *= alpha[r];
        #pragma unroll
        for (int r = 0; r < 4; ++r) o_l[r] *= alpha[r];

        // PV (+ row-sum via ones-B MFMA)
        half8 pa = *(const half8*)&Pw[l15 * 40 + quad * 8];
        o_l = __builtin_amdgcn_mfma_f32_16x16x32_f16(pa, ones_h, o_l, 0, 0, 0);
        #pragma unroll
        for (int nb = 0; nb < 8; ++nb) {
            int rv = nb * 16 + l15;
            int sig = rv * 4 + (quad ^ ((l15 >> 1) & 3));
            half8 vv = *(const half8*)&vb[sig * 8];
            o[nb] = __builtin_amdgcn_mfma_f32_16x16x32_f16(pa, vv, o[nb], 0, 0, 0);
        }
    }

    float inv[4];
    #pragma unroll
    for (int r = 0; r < 4; ++r) inv[r] = (o_l[r] > 0.f) ? 1.f / o_l[r] : 0.f;

    f16* po = part_o + (size_t)z * S_LEN * 2048;
    #pragma unroll
    for (int nb = 0; nb < 8; ++nb) {
        #pragma unroll
        for (int r = 0; r < 4; ++r) {
            int row = q0 + w * 16 + quad * 4 + r;
            po[(size_t)row * (NH * DV) + h * DV + nb * 16 + l15] =
                (f16)(o[nb][r] * inv[r]);
        }
    }
    if (l15 == 0) {
        #pragma unroll
        for (int r = 0; r < 4; ++r) {
            int row = q0 + w * 16 + quad * 4 + r;
            float* ml = part_ml + (((size_t)z * NH + h) * S_LEN + row) * 2;
            ml[0] = m_i[r];
            ml[1] = o_l[r];
        }
    }
}

// ---------------------------------------------------------------------------
// Combine the two split-K halves.
// ---------------------------------------------------------------------------
__global__ __launch_bounds__(256) void attn_comb_k(
    const f16* __restrict__ part_o, const float* __restrict__ part_ml,
    f16* __restrict__ attnb)
{
    int g = blockIdx.x * 256 + threadIdx.x;       // < 2048*2048/8
    int h = (g >> 4) & 15;
    int s = g >> 8;
    const float* ml0 = part_ml + ((size_t)h * S_LEN + s) * 2;
    const float* ml1 = part_ml + (((size_t)NH + h) * S_LEN + s) * 2;
    float m0 = ml0[0], l0 = ml0[1];
    float m1 = ml1[0], l1 = ml1[1];
    float M = fmaxf(m0, m1);
    float w0 = l0 * __builtin_exp2f(m0 - M);
    float w1 = l1 * __builtin_exp2f(m1 - M);
    float inv = 1.f / (w0 + w1);
    w0 *= inv; w1 *= inv;
    half8 p0 = *(const half8*)&part_o[(size_t)g * 8];
    half8 p1 = *(const half8*)&part_o[(size_t)(524288 + g) * 8];
    half8 r;
    #pragma unroll
    for (int j = 0; j < 8; ++j)
        r[j] = (f16)(w0 * (float)p0[j] + w1 * (float)p1[j]);
    *(half8*)&attnb[(size_t)g * 8] = r;
}

// ---------------------------------------------------------------------------
// Launch
// ---------------------------------------------------------------------------
extern "C" void kernel_launch(void* const* d_in, const int* in_sizes, int n_in,
                              void* d_out, int out_size, void* d_ws, size_t ws_size,
                              hipStream_t stream)
{
    const float* hidden   = (const float*)d_in[0];
    const float* w_kv_a   = (const float*)d_in[1];
    const float* q_gamma  = (const float*)d_in[2];
    const float* w_qb     = (const float*)d_in[3];
    const float* kv_gamma = (const float*)d_in[4];
    const float* w_kvb    = (const float*)d_in[5];
    const float* w_o      = (const float*)d_in[6];
    float* out = (float*)d_out;

    char* p = (char*)d_ws;
    f16* hid_h   = (f16*)p;  p += (size_t)2048 * 2048 * 2;
    f16* wkva_t  = (f16*)p;  p += (size_t)2176 * 2048 * 2;
    f16* wqb_t   = (f16*)p;  p += (size_t)3072 * 1536 * 2;
    f16* wkvb_t  = (f16*)p;  p += (size_t)4096 * 512 * 2;
    f16* wo_t    = (f16*)p;  p += (size_t)2048 * 2048 * 2;
    float* fused = (float*)p; p += (size_t)2048 * FPAD * 4;
    f16* q_n     = (f16*)p;  p += (size_t)2048 * QL * 2;
    f16* qbuf    = (f16*)p;  p += (size_t)2048 * QB_N * 2;
    f16* kv_n    = (f16*)p;  p += (size_t)2048 * KL * 2;
    f16* kvbuf   = (f16*)p;  p += (size_t)2048 * KVB_N * 2;
    f16* attnb   = (f16*)p;  p += (size_t)2048 * 2048 * 2;
    f16* part_o  = (f16*)p;  p += (size_t)2 * 2048 * 2048 * 2;
    float* part_ml = (float*)p; p += (size_t)2 * NH * 2048 * 2 * 4;

    // kfull aliases hid_h+wkva_t (dead after gemm1); vt gets fresh ws.
    f16* kfull = hid_h;
    f16* vt    = (f16*)p;   // fresh region, 8.4 MB

    dim3 blk(256);

    // prep: cvt + 4 weight transposes (one launch)
    prep_k<<<19200, blk, 0, stream>>>(hidden, hid_h, w_kv_a, wkva_t,
                                      w_qb, wqb_t, w_kvb, wkvb_t, w_o, wo_t);

    // 1. fused = hidden @ w_kv_a
    gemm_mfma<0><<<dim3(FPAD / 64, 16), blk, 0, stream>>>(
        hid_h, wkva_t, fused, FPAD, 2048);

    // 2. both RMSNorms (one launch)
    rmsnorm_k<<<4096, blk, 0, stream>>>(fused, q_gamma, kv_gamma, q_n, kv_n);

    // 3+4. q and kv up-projections fused
    gemm_dual<<<dim3(48 + 64, 16), blk, 0, stream>>>(
        q_n, wqb_t, qbuf, kv_n, wkvb_t, kvbuf);

    // 5. rope_q + kfull + vt (one launch)
    post_k<<<15360, blk, 0, stream>>>(qbuf, kvbuf, fused, kfull, vt);

    // 6. attention (split-K=2) + combine
    attn_mfma_k<<<dim3(32, NH, 2), blk, 0, stream>>>(qbuf, kfull, vt, part_o, part_ml);
    attn_comb_k<<<2048, blk, 0, stream>>>(part_o, part_ml, attnb);

    // 7. out = attn @ w_o
    gemm_mfma<0><<<dim3(2048 / 64, 16), blk, 0, stream>>>(
        attnb, wo_t, out, 2048, 2048);
}